// Round 1
// baseline (4896.370 us; speedup 1.0000x reference)
//
#include <hip/hip_runtime.h>

#define B_  8
#define N_  16384
#define D_  64
#define S_  2048
#define K_  32

// =====================================================================
// K1: per-point squared norms + new_xyz gather
// =====================================================================
__global__ __launch_bounds__(256) void k_prep(
    const float* __restrict__ xyz, const float* __restrict__ points,
    const int* __restrict__ sidx, float* __restrict__ out, float* __restrict__ sqn)
{
  int tid = blockIdx.x * 256 + threadIdx.x;      // 0 .. B*N-1
  const float4* p = (const float4*)(points + (size_t)tid * 64);
  float s = 0.f;
  #pragma unroll
  for (int i = 0; i < 16; ++i) {
    float4 v = p[i];
    s += v.x*v.x + v.y*v.y + v.z*v.z + v.w*v.w;
  }
  sqn[tid] = s;
  if (tid < B_*S_) {
    int b = tid >> 11, ss = tid & (S_-1);
    int n = sidx[ss];
    const float* src = xyz + ((size_t)b * N_ + n) * 3;
    out[(size_t)tid*3+0] = src[0];
    out[(size_t)tid*3+1] = src[1];
    out[(size_t)tid*3+2] = src[2];
  }
}

// =====================================================================
// K2: fused distance GEMM + exact top-32 selection
// =====================================================================
// sorted-descending 32-entry list insert (keeps 32 smallest; Lv[0] = largest kept)
__device__ __forceinline__ void insert32(float (&Lv)[32], int (&Li)[32], float x, int n)
{
  bool ci = x < Lv[0];
  #pragma unroll
  for (int i = 0; i < 31; ++i) {
    bool c1 = x < Lv[i+1];
    float nv = c1 ? Lv[i+1] : (ci ? x : Lv[i]);
    int   ni = c1 ? Li[i+1] : (ci ? n : Li[i]);
    Lv[i] = nv; Li[i] = ni;
    ci = c1;
  }
  Lv[31] = ci ? x : Lv[31];
  Li[31] = ci ? n : Li[31];
}

__global__ __launch_bounds__(256) void k_knn(
    const float* __restrict__ points, const int* __restrict__ sidx,
    const float* __restrict__ sqn, int* __restrict__ nbr)
{
  __shared__ float sm[16384];          // 64 KiB, aliased across phases
  float* At  = sm;                     // [64 c][68] transposed A tile
  float* Bt  = sm + 4352;              // [64 c][68] transposed B chunk
  float* Dt  = sm + 8704;              // [64 r][68] key tile
  float* sqc = sm + 13056;             // [64]
  int*   sIx = (int*)(sm + 13120);     // [64]

  const int t = threadIdx.x;
  // XCD-swizzle: consecutive blocks = same tile, different b -> each XCD mostly one b
  const int b    = blockIdx.x & 7;
  const int tile = blockIdx.x >> 3;
  const int s0   = tile * 64;
  const float* Pb = points + (size_t)b * N_ * 64;
  const float* Qb = sqn    + (size_t)b * N_;

  if (t < 64) sIx[t] = sidx[s0 + t];
  __syncthreads();

  // stage A tile (64 sampled rows), transposed into At[c][s]
  {
    const int i = t & 63, j4 = t >> 6;
    const float* src = Pb + (size_t)sIx[i] * 64;
    #pragma unroll
    for (int k = 0; k < 4; ++k) {
      int j = j4 * 4 + k;
      float4 v = *(const float4*)(src + j * 4);
      At[(4*j+0)*68 + i] = v.x; At[(4*j+1)*68 + i] = v.y;
      At[(4*j+2)*68 + i] = v.z; At[(4*j+3)*68 + i] = v.w;
    }
  }

  float Lv[32]; int Li[32];
  #pragma unroll
  for (int i = 0; i < 32; ++i) { Lv[i] = 3.0e38f; Li[i] = 0; }

  const int r  = t >> 2;        // selection row 0..63
  const int q  = t & 3;         // stream id within row
  const int r0 = (t & 15) * 4;  // gemm row base
  const int c0 = (t >> 4) * 4;  // gemm col base

  for (int ch = 0; ch < 256; ++ch) {
    const int n0 = ch * 64;
    __syncthreads();            // prev chunk fully consumed
    // stage B chunk transposed + sqnorm chunk
    {
      const int i = t & 63, j4 = t >> 6;
      const float* src = Pb + (size_t)(n0 + i) * 64;
      #pragma unroll
      for (int k = 0; k < 4; ++k) {
        int j = j4 * 4 + k;
        float4 v = *(const float4*)(src + j * 4);
        Bt[(4*j+0)*68 + i] = v.x; Bt[(4*j+1)*68 + i] = v.y;
        Bt[(4*j+2)*68 + i] = v.z; Bt[(4*j+3)*68 + i] = v.w;
      }
      if (t < 16) *(float4*)(sqc + t*4) = *(const float4*)(Qb + n0 + t*4);
    }
    __syncthreads();

    // 64x64x64 fp32 GEMM, 4x4 per thread
    float acc[4][4];
    #pragma unroll
    for (int i = 0; i < 4; ++i) { acc[i][0]=0.f; acc[i][1]=0.f; acc[i][2]=0.f; acc[i][3]=0.f; }
    #pragma unroll 4
    for (int c = 0; c < 64; ++c) {
      float4 av = *(const float4*)(At + c*68 + r0);
      float4 bv = *(const float4*)(Bt + c*68 + c0);
      float a4[4] = {av.x, av.y, av.z, av.w};
      float b4[4] = {bv.x, bv.y, bv.z, bv.w};
      #pragma unroll
      for (int i = 0; i < 4; ++i)
        #pragma unroll
        for (int j = 0; j < 4; ++j)
          acc[i][j] = fmaf(a4[i], b4[j], acc[i][j]);
    }
    // ranking keys: |p_n|^2 - 2*dot  (row-constant |a|^2 dropped: same ranking)
    #pragma unroll
    for (int i = 0; i < 4; ++i) {
      float4 kv;
      kv.x = sqc[c0+0] - 2.f*acc[i][0];
      kv.y = sqc[c0+1] - 2.f*acc[i][1];
      kv.z = sqc[c0+2] - 2.f*acc[i][2];
      kv.w = sqc[c0+3] - 2.f*acc[i][3];
      *(float4*)(Dt + (r0+i)*68 + c0) = kv;
    }
    __syncthreads();

    // row-level threshold: min of the 4 stream-threads' current 32nd value.
    // Valid upper bound on the row's true running 32nd value -> exact filter.
    float L0 = Lv[0];
    L0 = fminf(L0, __shfl_xor(L0, 1));
    L0 = fminf(L0, __shfl_xor(L0, 2));
    const float tau = L0;

    for (int g = 0; g < 4; ++g) {
      float4 kv = *(const float4*)(Dt + r*68 + q*16 + g*4);
      float x4[4] = {kv.x, kv.y, kv.z, kv.w};
      const int nb = n0 + q*16 + g*4;
      #pragma unroll
      for (int u = 0; u < 4; ++u) {
        float x = x4[u];
        if (x < fminf(tau, Lv[0]))
          insert32(Lv, Li, x, nb + u);
      }
    }
  }

  // -------- final merge: 4 sorted lists per row -> exact top-32 --------
  __syncthreads();
  float* bufV = sm;                    // [64][128] (bank-swizzled by +r)
  int*   bufI = (int*)(sm + 8192);
  #pragma unroll
  for (int i = 0; i < 32; ++i) {
    int ph = ((q*32 + i) + r) & 127;
    bufV[r*128 + ph] = Lv[i];
    bufI[r*128 + ph] = Li[i];
  }
  __syncthreads();
  if (t < 64) {
    const int rr = t;
    int* dst = nbr + (size_t)(b * S_ + s0 + rr) * K_;
    for (int k = 0; k < K_; ++k) {
      float mv = 3.0e38f; int mi = 0x7fffffff; int me = 0;
      for (int j = 0; j < 128; ++j) {
        int ph = (j + rr) & 127;
        float v  = bufV[rr*128 + ph];
        int   id = bufI[rr*128 + ph];
        bool better = (v < mv) | ((v == mv) & (id < mi));
        if (better) { mv = v; mi = id; me = ph; }
      }
      dst[k] = mi;
      bufV[rr*128 + me] = 3.0e38f;
    }
  }
}

// =====================================================================
// K3: gather + 3-layer MLP (BN folded) + maxpool over 32 neighbors
// =====================================================================
__device__ __forceinline__ void layer64(
    const int t, const float* __restrict__ w, const float* __restrict__ bb,
    const float* __restrict__ gg, const float* __restrict__ be,
    const float* __restrict__ mm, const float* __restrict__ vv,
    const float* Xin, float* Hout, float* W, float* scl, float* bia)
{
  if (t < 64) {
    float sc = gg[t] * rsqrtf(vv[t] + 1e-5f);
    scl[t] = sc;
    bia[t] = (bb[t] - mm[t]) * sc + be[t];
  }
  __syncthreads();
  #pragma unroll
  for (int k = 0; k < 4; ++k) {
    int flat = k*256 + t;
    int o = flat >> 4, j = flat & 15;
    float4 v = *(const float4*)(w + o*64 + j*4);
    float sc = scl[o];
    v.x *= sc; v.y *= sc; v.z *= sc; v.w *= sc;
    *(float4*)(W + o*68 + j*4) = v;
  }
  __syncthreads();
  const int o0 = (t & 15) * 4;
  const int rp = t >> 4;
  float acc[2][4] = {};
  #pragma unroll 4
  for (int c4 = 0; c4 < 16; ++c4) {
    float4 xa = *(const float4*)(Xin + (2*rp)*68   + c4*4);
    float4 xb = *(const float4*)(Xin + (2*rp+1)*68 + c4*4);
    #pragma unroll
    for (int j = 0; j < 4; ++j) {
      float4 wv = *(const float4*)(W + (o0+j)*68 + c4*4);
      acc[0][j] = fmaf(xa.x,wv.x, fmaf(xa.y,wv.y, fmaf(xa.z,wv.z, fmaf(xa.w,wv.w, acc[0][j]))));
      acc[1][j] = fmaf(xb.x,wv.x, fmaf(xb.y,wv.y, fmaf(xb.z,wv.z, fmaf(xb.w,wv.w, acc[1][j]))));
    }
  }
  #pragma unroll
  for (int j = 0; j < 4; ++j) {
    Hout[(2*rp)*68   + o0+j] = fmaxf(acc[0][j] + bia[o0+j], 0.f);
    Hout[(2*rp+1)*68 + o0+j] = fmaxf(acc[1][j] + bia[o0+j], 0.f);
  }
  __syncthreads();
}

__global__ __launch_bounds__(256) void k_mlp(
    const float* __restrict__ points, const int* __restrict__ nbr,
    const float* __restrict__ w0, const float* __restrict__ b0,
    const float* __restrict__ g0, const float* __restrict__ be0,
    const float* __restrict__ m0, const float* __restrict__ v0,
    const float* __restrict__ w1, const float* __restrict__ b1,
    const float* __restrict__ g1, const float* __restrict__ be1,
    const float* __restrict__ m1, const float* __restrict__ v1,
    const float* __restrict__ w2, const float* __restrict__ b2,
    const float* __restrict__ g2, const float* __restrict__ be2,
    const float* __restrict__ m2, const float* __restrict__ v2,
    float* __restrict__ out)
{
  __shared__ float X[32*68];
  __shared__ float H[32*68];     // also reused as maxpool partial buffer
  __shared__ float W[128*68];
  __shared__ float scl[128];
  __shared__ float bia[128];
  __shared__ int   nIx[32];

  const int t  = threadIdx.x;
  const int bs = blockIdx.x;
  const int b  = bs >> 11;

  if (t < 32) nIx[t] = nbr[(size_t)bs * K_ + t];
  __syncthreads();
  #pragma unroll
  for (int k = 0; k < 2; ++k) {
    int flat = k*256 + t;
    int row = flat >> 4, j = flat & 15;
    float4 v = *(const float4*)(points + ((size_t)b*N_ + nIx[row])*64 + j*4);
    *(float4*)(X + row*68 + j*4) = v;
  }
  __syncthreads();

  layer64(t, w0, b0, g0, be0, m0, v0, X, H, W, scl, bia);   // X -> H
  layer64(t, w1, b1, g1, be1, m1, v1, H, X, W, scl, bia);   // H -> X

  // ---- layer 2: 64 -> 128, fused relu + maxpool ----
  if (t < 128) {
    float sc = g2[t] * rsqrtf(v2[t] + 1e-5f);
    scl[t] = sc;
    bia[t] = (b2[t] - m2[t]) * sc + be2[t];
  }
  __syncthreads();
  #pragma unroll
  for (int k = 0; k < 8; ++k) {
    int flat = k*256 + t;
    int o = flat >> 4, j = flat & 15;
    float4 v = *(const float4*)(w2 + o*64 + j*4);
    float sc = scl[o];
    v.x *= sc; v.y *= sc; v.z *= sc; v.w *= sc;
    *(float4*)(W + o*68 + j*4) = v;
  }
  __syncthreads();
  {
    const int o0 = (t & 31) * 4;
    const int rq = t >> 5;
    float acc[4][4] = {};
    #pragma unroll 4
    for (int c4 = 0; c4 < 16; ++c4) {
      float4 xr[4];
      #pragma unroll
      for (int i = 0; i < 4; ++i) xr[i] = *(const float4*)(X + (4*rq+i)*68 + c4*4);
      #pragma unroll
      for (int j = 0; j < 4; ++j) {
        float4 wv = *(const float4*)(W + (o0+j)*68 + c4*4);
        #pragma unroll
        for (int i = 0; i < 4; ++i)
          acc[i][j] = fmaf(xr[i].x,wv.x, fmaf(xr[i].y,wv.y, fmaf(xr[i].z,wv.z, fmaf(xr[i].w,wv.w, acc[i][j]))));
      }
    }
    float pm[4];
    #pragma unroll
    for (int j = 0; j < 4; ++j) {
      float m = -3.0e38f;
      #pragma unroll
      for (int i = 0; i < 4; ++i)
        m = fmaxf(m, fmaxf(acc[i][j] + bia[o0+j], 0.f));
      pm[j] = m;
    }
    __syncthreads();
    *(float4*)(H + rq*132 + o0) = make_float4(pm[0], pm[1], pm[2], pm[3]);
  }
  __syncthreads();
  if (t < 128) {
    float m = -3.0e38f;
    #pragma unroll
    for (int rq = 0; rq < 8; ++rq) m = fmaxf(m, H[rq*132 + t]);
    out[(size_t)(B_*S_*3) + (size_t)bs*128 + t] = m;
  }
}

// =====================================================================
extern "C" void kernel_launch(void* const* d_in, const int* in_sizes, int n_in,
                              void* d_out, int out_size, void* d_ws, size_t ws_size,
                              hipStream_t stream)
{
  const float* xyz  = (const float*)d_in[0];
  const float* pts  = (const float*)d_in[1];
  const int*   sidx = (const int*)  d_in[2];
  const float* w0 = (const float*)d_in[3];
  const float* b0 = (const float*)d_in[4];
  const float* g0 = (const float*)d_in[5];
  const float* be0= (const float*)d_in[6];
  const float* m0 = (const float*)d_in[7];
  const float* v0 = (const float*)d_in[8];
  const float* w1 = (const float*)d_in[9];
  const float* b1 = (const float*)d_in[10];
  const float* g1 = (const float*)d_in[11];
  const float* be1= (const float*)d_in[12];
  const float* m1 = (const float*)d_in[13];
  const float* v1 = (const float*)d_in[14];
  const float* w2 = (const float*)d_in[15];
  const float* b2 = (const float*)d_in[16];
  const float* g2 = (const float*)d_in[17];
  const float* be2= (const float*)d_in[18];
  const float* m2 = (const float*)d_in[19];
  const float* v2 = (const float*)d_in[20];

  float* out = (float*)d_out;
  float* sqn = (float*)d_ws;                                  // B*N floats (512 KiB)
  int*   nbr = (int*)((char*)d_ws + (size_t)B_*N_*sizeof(float)); // B*S*32 ints (2 MiB)

  k_prep<<<(B_*N_)/256, 256, 0, stream>>>(xyz, pts, sidx, out, sqn);
  k_knn <<<B_*(S_/64),  256, 0, stream>>>(pts, sidx, sqn, nbr);
  k_mlp <<<B_*S_,       256, 0, stream>>>(pts, nbr,
            w0,b0,g0,be0,m0,v0, w1,b1,g1,be1,m1,v1, w2,b2,g2,be2,m2,v2, out);
}

// Round 3
// 3502.274 us; speedup vs baseline: 1.3981x; 1.3981x over previous
//
#include <hip/hip_runtime.h>

#define B_  8
#define N_  16384
#define D_  64
#define S_  2048
#define K_  32
#define SPLIT_  4
#define NSPL_   (N_/SPLIT_)     // 4096 candidates per block
#define CHUNKS_ (NSPL_/64)      // 64 chunks of 64

using short8_ = __attribute__((ext_vector_type(8))) short;
using f32x4_  = __attribute__((ext_vector_type(4))) float;

// =====================================================================
// exact bf16 triple-split of fp32 (truncation-based, bitwise exact):
// f = bf(h0) + bf(h1) + bf(h2)
// =====================================================================
__device__ __forceinline__ void bf3split(float f, short& h0, short& h1, short& h2)
{
  unsigned u0 = __float_as_uint(f);
  float f0 = __uint_as_float(u0 & 0xFFFF0000u);
  h0 = (short)(u0 >> 16);
  float r1 = f - f0;
  unsigned u1 = __float_as_uint(r1);
  float f1 = __uint_as_float(u1 & 0xFFFF0000u);
  h1 = (short)(u1 >> 16);
  float r2 = r1 - f1;                 // <= 8 significant bits: bf16-exact
  h2 = (short)(__float_as_uint(r2) >> 16);
}

// =====================================================================
// K1: per-point squared norms + new_xyz gather
// =====================================================================
__global__ __launch_bounds__(256) void k_prep(
    const float* __restrict__ xyz, const float* __restrict__ points,
    const int* __restrict__ sidx, float* __restrict__ out, float* __restrict__ sqn)
{
  int tid = blockIdx.x * 256 + threadIdx.x;      // 0 .. B*N-1
  const float4* p = (const float4*)(points + (size_t)tid * 64);
  float s = 0.f;
  #pragma unroll
  for (int i = 0; i < 16; ++i) {
    float4 v = p[i];
    s += v.x*v.x + v.y*v.y + v.z*v.z + v.w*v.w;
  }
  sqn[tid] = s;
  if (tid < B_*S_) {
    int b = tid >> 11, ss = tid & (S_-1);
    int n = sidx[ss];
    const float* src = xyz + ((size_t)b * N_ + n) * 3;
    out[(size_t)tid*3+0] = src[0];
    out[(size_t)tid*3+1] = src[1];
    out[(size_t)tid*3+2] = src[2];
  }
}

// =====================================================================
// K2: MFMA bf16x3 (exact-split) distance GEMM + exact top-32 (split-N)
// =====================================================================
// sorted-DESCENDING 32-entry list (Lv[0] = largest kept, Lv[31] = smallest)
__device__ __forceinline__ void insert32(float (&Lv)[32], int (&Li)[32], float x, int n)
{
  bool ci = x < Lv[0];
  #pragma unroll
  for (int i = 0; i < 31; ++i) {
    bool c1 = x < Lv[i+1];
    float nv = c1 ? Lv[i+1] : (ci ? x : Lv[i]);
    int   ni = c1 ? Li[i+1] : (ci ? n : Li[i]);
    Lv[i] = nv; Li[i] = ni;
    ci = c1;
  }
  Lv[31] = ci ? x : Lv[31];
  Li[31] = ci ? n : Li[31];
}

__global__ __launch_bounds__(256) void k_knn(
    const float* __restrict__ points, const int* __restrict__ sidx,
    const float* __restrict__ sqn, uint2* __restrict__ pw)
{
  // LDS: B planes 0..2 (bf16 [64][72], 9216 B each) | Dt col-major [64c][68r] f32 | sqc
  // merge phase aliases front as uint2 mbuf[32][130] (33280 B)
  __shared__ __align__(16) char smraw[45312];
  short* Bp0 = (short*)smraw;
  short* Bp1 = (short*)(smraw + 9216);
  short* Bp2 = (short*)(smraw + 18432);
  float* Dt  = (float*)(smraw + 27648);
  float* sqc = (float*)(smraw + 45056);

  const int t = threadIdx.x;
  const int b     = blockIdx.x & 7;          // XCD swizzle
  const int y     = blockIdx.x >> 3;
  const int tile  = y & 31;
  const int split = y >> 5;
  const int s0 = tile * 64;
  const float* Pb = points + (size_t)b * N_ * 64;
  const float* Qb = sqn    + (size_t)b * N_;

  const int lane = t & 63, wv = t >> 6;
  const int quad = lane >> 4, mcol = lane & 15;

  // ---- A fragments in registers: wave wv owns sampled rows 16*wv..+15 ----
  // A layout (16x16x32): A[m=lane&15][k=quad*8+j]; kt covers k 0..31 / 32..63
  short8_ A0[2], A1[2], A2[2];
  {
    int srow = sidx[s0 + 16*wv + mcol];
    const float* ar = Pb + (size_t)srow * 64;
    #pragma unroll
    for (int kt = 0; kt < 2; ++kt) {
      float4 v0 = *(const float4*)(ar + 32*kt + 8*quad);
      float4 v1 = *(const float4*)(ar + 32*kt + 8*quad + 4);
      float f[8] = {v0.x,v0.y,v0.z,v0.w,v1.x,v1.y,v1.z,v1.w};
      #pragma unroll
      for (int j = 0; j < 8; ++j) {
        short h0, h1, h2;
        bf3split(f[j], h0, h1, h2);
        A0[kt][j] = h0; A1[kt][j] = h1; A2[kt][j] = h2;
      }
    }
  }

  float Lv[32]; int Li[32];
  #pragma unroll
  for (int i = 0; i < 32; ++i) { Lv[i] = 3.0e38f; Li[i] = 0; }

  const int r = t >> 2;        // selection row 0..63
  const int q = t & 3;         // stream within row
  const int n0base = split * NSPL_;

  for (int ch = 0; ch < CHUNKS_; ++ch) {
    const int n0 = n0base + ch * 64;
    // ---- stage B chunk in 3 bf16 planes, layout [n][k] pitch 72 ----
    {
      const int n = t & 63, jg = t >> 6;     // 16 dims per thread
      const float* src = Pb + (size_t)(n0 + n) * 64 + 16*jg;
      float4 u0 = *(const float4*)(src);
      float4 u1 = *(const float4*)(src + 4);
      float4 u2 = *(const float4*)(src + 8);
      float4 u3 = *(const float4*)(src + 12);
      float f[16] = {u0.x,u0.y,u0.z,u0.w, u1.x,u1.y,u1.z,u1.w,
                     u2.x,u2.y,u2.z,u2.w, u3.x,u3.y,u3.z,u3.w};
      short8_ p0[2], p1[2], p2[2];
      #pragma unroll
      for (int j = 0; j < 16; ++j) {
        short h0, h1, h2;
        bf3split(f[j], h0, h1, h2);
        p0[j>>3][j&7] = h0; p1[j>>3][j&7] = h1; p2[j>>3][j&7] = h2;
      }
      *(short8_*)(Bp0 + n*72 + 16*jg)     = p0[0];
      *(short8_*)(Bp0 + n*72 + 16*jg + 8) = p0[1];
      *(short8_*)(Bp1 + n*72 + 16*jg)     = p1[0];
      *(short8_*)(Bp1 + n*72 + 16*jg + 8) = p1[1];
      *(short8_*)(Bp2 + n*72 + 16*jg)     = p2[0];
      *(short8_*)(Bp2 + n*72 + 16*jg + 8) = p2[1];
      if (t < 16) *(float4*)(sqc + 4*t) = *(const float4*)(Qb + n0 + 4*t);
    }
    __syncthreads();

    // ---- 16 MFMA per 16x16 tile: all aibj except a2b2 (~1e-8 dropped) ----
    f32x4_ acc[4];
    #pragma unroll
    for (int ct = 0; ct < 4; ++ct) {
      const int boff = (16*ct + mcol)*72 + 8*quad;
      short8_ b0[2], b1[2], b2[2];
      b0[0] = *(const short8_*)(Bp0 + boff); b0[1] = *(const short8_*)(Bp0 + boff + 32);
      b1[0] = *(const short8_*)(Bp1 + boff); b1[1] = *(const short8_*)(Bp1 + boff + 32);
      b2[0] = *(const short8_*)(Bp2 + boff); b2[1] = *(const short8_*)(Bp2 + boff + 32);
      f32x4_ a = {0.f, 0.f, 0.f, 0.f};
      #pragma unroll
      for (int kt = 0; kt < 2; ++kt) {
        a = __builtin_amdgcn_mfma_f32_16x16x32_bf16(A0[kt], b0[kt], a, 0,0,0);
        a = __builtin_amdgcn_mfma_f32_16x16x32_bf16(A0[kt], b1[kt], a, 0,0,0);
        a = __builtin_amdgcn_mfma_f32_16x16x32_bf16(A1[kt], b0[kt], a, 0,0,0);
        a = __builtin_amdgcn_mfma_f32_16x16x32_bf16(A1[kt], b1[kt], a, 0,0,0);
        a = __builtin_amdgcn_mfma_f32_16x16x32_bf16(A0[kt], b2[kt], a, 0,0,0);
        a = __builtin_amdgcn_mfma_f32_16x16x32_bf16(A2[kt], b0[kt], a, 0,0,0);
        a = __builtin_amdgcn_mfma_f32_16x16x32_bf16(A1[kt], b2[kt], a, 0,0,0);
        a = __builtin_amdgcn_mfma_f32_16x16x32_bf16(A2[kt], b1[kt], a, 0,0,0);
      }
      acc[ct] = a;
    }
    // ---- keys -> Dt col-major. C/D: col=lane&15, row=quad*4+reg ----
    #pragma unroll
    for (int ct = 0; ct < 4; ++ct) {
      int c = 16*ct + mcol;
      float sq = sqc[c];
      float4 kv;
      kv.x = sq - 2.f*acc[ct][0];
      kv.y = sq - 2.f*acc[ct][1];
      kv.z = sq - 2.f*acc[ct][2];
      kv.w = sq - 2.f*acc[ct][3];
      *(float4*)(Dt + c*68 + 16*wv + 4*quad) = kv;
    }
    __syncthreads();

    // ---- exact top-32 selection, tau-filtered ----
    float L0 = Lv[0];
    L0 = fminf(L0, __shfl_xor(L0, 1));
    L0 = fminf(L0, __shfl_xor(L0, 2));
    const float tau = L0;
    #pragma unroll
    for (int g = 0; g < 4; ++g) {
      #pragma unroll
      for (int u = 0; u < 4; ++u) {
        int c = q*16 + g*4 + u;
        float x = Dt[c*68 + r];
        if (x < fminf(tau, Lv[0]))
          insert32(Lv, Li, x, n0 + c);
      }
    }
  }

  // ---- in-block 4-pointer merge of the 4 sorted streams per row ----
  // Lv is DESCENDING: store reversed so each stream segment is ASCENDING.
  uint2* mbuf = (uint2*)smraw;                 // [32][130]
  const int rowg = b * S_ + s0;
  for (int pass = 0; pass < 2; ++pass) {
    __syncthreads();
    const int rb = pass * 32;
    if (r >= rb && r < rb + 32) {
      #pragma unroll
      for (int i = 0; i < 32; ++i)
        mbuf[(r - rb)*130 + q*32 + (31 - i)] =
            make_uint2(__float_as_uint(Lv[i]), (unsigned)Li[i]);
    }
    __syncthreads();
    if (t < 32) {
      const uint2* Lrow = mbuf + t*130;
      uint2* dst = pw + ((size_t)(rowg + rb + t) * SPLIT_ + split) * 32;
      int p0 = 0, p1 = 0, p2 = 0, p3 = 0;
      for (int k = 0; k < 32; ++k) {
        float bv = 3.0e38f; unsigned bi = 0xFFFFFFFFu; int bq = 0;
        int pa[4] = {p0, p1, p2, p3};
        #pragma unroll
        for (int q4 = 0; q4 < 4; ++q4) {
          if (pa[q4] < 32) {
            uint2 e = Lrow[q4*32 + pa[q4]];
            float v = __uint_as_float(e.x);
            if (v < bv || (v == bv && e.y < bi)) { bv = v; bi = e.y; bq = q4; }
          }
        }
        dst[k] = make_uint2(__float_as_uint(bv), bi);
        if (bq == 0) p0++; else if (bq == 1) p1++; else if (bq == 2) p2++; else p3++;
      }
    }
  }
}

// =====================================================================
// K2b: merge the 4 split-partials (ascending) per row -> 32 indices
// =====================================================================
__global__ __launch_bounds__(256) void k_sel(const uint2* __restrict__ pw,
                                             int* __restrict__ nbr)
{
  int row = blockIdx.x * 256 + threadIdx.x;       // 0 .. B*S-1
  const uint2* L = pw + (size_t)row * (SPLIT_*32);
  int* dst = nbr + (size_t)row * K_;
  int p[4] = {0,0,0,0};
  for (int k = 0; k < K_; ++k) {
    float bv = 3.0e38f; unsigned bi = 0xFFFFFFFFu; int bq = 0;
    #pragma unroll
    for (int q4 = 0; q4 < 4; ++q4) {
      if (p[q4] < 32) {
        uint2 e = L[q4*32 + p[q4]];
        float v = __uint_as_float(e.x);
        if (v < bv || (v == bv && e.y < bi)) { bv = v; bi = e.y; bq = q4; }
      }
    }
    dst[k] = (int)bi;
    p[bq]++;
  }
}

// =====================================================================
// K3: gather + 3-layer MLP (BN folded) + maxpool over 32 neighbors
// =====================================================================
__device__ __forceinline__ void layer64(
    const int t, const float* __restrict__ w, const float* __restrict__ bb,
    const float* __restrict__ gg, const float* __restrict__ be,
    const float* __restrict__ mm, const float* __restrict__ vv,
    const float* Xin, float* Hout, float* W, float* scl, float* bia)
{
  if (t < 64) {
    float sc = gg[t] * rsqrtf(vv[t] + 1e-5f);
    scl[t] = sc;
    bia[t] = (bb[t] - mm[t]) * sc + be[t];
  }
  __syncthreads();
  #pragma unroll
  for (int k = 0; k < 4; ++k) {
    int flat = k*256 + t;
    int o = flat >> 4, j = flat & 15;
    float4 v = *(const float4*)(w + o*64 + j*4);
    float sc = scl[o];
    v.x *= sc; v.y *= sc; v.z *= sc; v.w *= sc;
    *(float4*)(W + o*68 + j*4) = v;
  }
  __syncthreads();
  const int o0 = (t & 15) * 4;
  const int rp = t >> 4;
  float acc[2][4] = {};
  #pragma unroll 4
  for (int c4 = 0; c4 < 16; ++c4) {
    float4 xa = *(const float4*)(Xin + (2*rp)*68   + c4*4);
    float4 xb = *(const float4*)(Xin + (2*rp+1)*68 + c4*4);
    #pragma unroll
    for (int j = 0; j < 4; ++j) {
      float4 wv = *(const float4*)(W + (o0+j)*68 + c4*4);
      acc[0][j] = fmaf(xa.x,wv.x, fmaf(xa.y,wv.y, fmaf(xa.z,wv.z, fmaf(xa.w,wv.w, acc[0][j]))));
      acc[1][j] = fmaf(xb.x,wv.x, fmaf(xb.y,wv.y, fmaf(xb.z,wv.z, fmaf(xb.w,wv.w, acc[1][j]))));
    }
  }
  #pragma unroll
  for (int j = 0; j < 4; ++j) {
    Hout[(2*rp)*68   + o0+j] = fmaxf(acc[0][j] + bia[o0+j], 0.f);
    Hout[(2*rp+1)*68 + o0+j] = fmaxf(acc[1][j] + bia[o0+j], 0.f);
  }
  __syncthreads();
}

__global__ __launch_bounds__(256) void k_mlp(
    const float* __restrict__ points, const int* __restrict__ nbr,
    const float* __restrict__ w0, const float* __restrict__ b0,
    const float* __restrict__ g0, const float* __restrict__ be0,
    const float* __restrict__ m0, const float* __restrict__ v0,
    const float* __restrict__ w1, const float* __restrict__ b1,
    const float* __restrict__ g1, const float* __restrict__ be1,
    const float* __restrict__ m1, const float* __restrict__ v1,
    const float* __restrict__ w2, const float* __restrict__ b2,
    const float* __restrict__ g2, const float* __restrict__ be2,
    const float* __restrict__ m2, const float* __restrict__ v2,
    float* __restrict__ out)
{
  __shared__ float X[32*68];
  __shared__ float H[32*68];
  __shared__ float W[128*68];
  __shared__ float scl[128];
  __shared__ float bia[128];
  __shared__ int   nIx[32];

  const int t  = threadIdx.x;
  const int bs = blockIdx.x;
  const int b  = bs >> 11;

  if (t < 32) nIx[t] = nbr[(size_t)bs * K_ + t];
  __syncthreads();
  #pragma unroll
  for (int k = 0; k < 2; ++k) {
    int flat = k*256 + t;
    int row = flat >> 4, j = flat & 15;
    float4 v = *(const float4*)(points + ((size_t)b*N_ + nIx[row])*64 + j*4);
    *(float4*)(X + row*68 + j*4) = v;
  }
  __syncthreads();

  layer64(t, w0, b0, g0, be0, m0, v0, X, H, W, scl, bia);   // X -> H
  layer64(t, w1, b1, g1, be1, m1, v1, H, X, W, scl, bia);   // H -> X

  if (t < 128) {
    float sc = g2[t] * rsqrtf(v2[t] + 1e-5f);
    scl[t] = sc;
    bia[t] = (b2[t] - m2[t]) * sc + be2[t];
  }
  __syncthreads();
  #pragma unroll
  for (int k = 0; k < 8; ++k) {
    int flat = k*256 + t;
    int o = flat >> 4, j = flat & 15;
    float4 v = *(const float4*)(w2 + o*64 + j*4);
    float sc = scl[o];
    v.x *= sc; v.y *= sc; v.z *= sc; v.w *= sc;
    *(float4*)(W + o*68 + j*4) = v;
  }
  __syncthreads();
  {
    const int o0 = (t & 31) * 4;
    const int rq = t >> 5;
    float acc[4][4] = {};
    #pragma unroll 4
    for (int c4 = 0; c4 < 16; ++c4) {
      float4 xr[4];
      #pragma unroll
      for (int i = 0; i < 4; ++i) xr[i] = *(const float4*)(X + (4*rq+i)*68 + c4*4);
      #pragma unroll
      for (int j = 0; j < 4; ++j) {
        float4 wv = *(const float4*)(W + (o0+j)*68 + c4*4);
        #pragma unroll
        for (int i = 0; i < 4; ++i)
          acc[i][j] = fmaf(xr[i].x,wv.x, fmaf(xr[i].y,wv.y, fmaf(xr[i].z,wv.z, fmaf(xr[i].w,wv.w, acc[i][j]))));
      }
    }
    float pm[4];
    #pragma unroll
    for (int j = 0; j < 4; ++j) {
      float m = -3.0e38f;
      #pragma unroll
      for (int i = 0; i < 4; ++i)
        m = fmaxf(m, fmaxf(acc[i][j] + bia[o0+j], 0.f));
      pm[j] = m;
    }
    __syncthreads();
    *(float4*)(H + rq*132 + o0) = make_float4(pm[0], pm[1], pm[2], pm[3]);
  }
  __syncthreads();
  if (t < 128) {
    float m = -3.0e38f;
    #pragma unroll
    for (int rq = 0; rq < 8; ++rq) m = fmaxf(m, H[rq*132 + t]);
    out[(size_t)(B_*S_*3) + (size_t)bs*128 + t] = m;
  }
}

// =====================================================================
extern "C" void kernel_launch(void* const* d_in, const int* in_sizes, int n_in,
                              void* d_out, int out_size, void* d_ws, size_t ws_size,
                              hipStream_t stream)
{
  const float* xyz  = (const float*)d_in[0];
  const float* pts  = (const float*)d_in[1];
  const int*   sidx = (const int*)  d_in[2];
  const float* w0 = (const float*)d_in[3];
  const float* b0 = (const float*)d_in[4];
  const float* g0 = (const float*)d_in[5];
  const float* be0= (const float*)d_in[6];
  const float* m0 = (const float*)d_in[7];
  const float* v0 = (const float*)d_in[8];
  const float* w1 = (const float*)d_in[9];
  const float* b1 = (const float*)d_in[10];
  const float* g1 = (const float*)d_in[11];
  const float* be1= (const float*)d_in[12];
  const float* m1 = (const float*)d_in[13];
  const float* v1 = (const float*)d_in[14];
  const float* w2 = (const float*)d_in[15];
  const float* b2 = (const float*)d_in[16];
  const float* g2 = (const float*)d_in[17];
  const float* be2= (const float*)d_in[18];
  const float* m2 = (const float*)d_in[19];
  const float* v2 = (const float*)d_in[20];

  float* out = (float*)d_out;
  // ws: sqn (B*N f32 = 512KB) | nbr (B*S*32 int = 2MB) | pw (B*S*4*32 uint2 = 16.8MB)
  float* sqn = (float*)d_ws;
  int*   nbr = (int*)  ((char*)d_ws + (size_t)B_*N_*4);
  uint2* pw  = (uint2*)((char*)d_ws + (size_t)B_*N_*4 + (size_t)B_*S_*K_*4);

  k_prep<<<(B_*N_)/256, 256, 0, stream>>>(xyz, pts, sidx, out, sqn);
  k_knn <<<B_*32*SPLIT_, 256, 0, stream>>>(pts, sidx, sqn, pw);
  k_sel <<<(B_*S_)/256, 256, 0, stream>>>(pw, nbr);
  k_mlp <<<B_*S_, 256, 0, stream>>>(pts, nbr,
            w0,b0,g0,be0,m0,v0, w1,b1,g1,be1,m1,v1, w2,b2,g2,be2,m2,v2, out);
}